// Round 1
// baseline (9061.806 us; speedup 1.0000x reference)
//
#include <hip/hip_runtime.h>
#include <stdint.h>
#include <math.h>

// ============================================================================
// POGLM.sample — bit-exact replication of the JAX-CPU reference.
// Variant knobs (flip across rounds if spikes diverge; see theory):
#define THREEFRY_PARTITIONABLE 1  // JAX >= 0.4.36 default key derivation
#define BITS32_XOR 1              // partitionable 32-bit draw = o0 ^ o1
#define VSL_FMA 0                 // XLA VectorSupportLibrary MulAdd: 0 = Add(Mul) unfused
#define CONV_FMA 0                // conv gemv chain: 0 = unfused mul+add (VSL), 1 = fmaf
// z-chain: Eigen gemm -> fused FMA ascending k (hard-coded).
// logistic: 1/(1+exp(-x)); exp/log: XLA Cephes (llvm_ir_runtime.cc).
// ============================================================================

#define T_BINS 1024
#define N_SAMP 64
#define N_NEUR 256
#define J_MAX 32

// --- strict (non-contractable) f32 ops ---
static __device__ __forceinline__ float fmul_s(float a, float b) {
#pragma clang fp contract(off)
  return a * b;
}
static __device__ __forceinline__ float fadd_s(float a, float b) {
#pragma clang fp contract(off)
  return a + b;
}
static __device__ __forceinline__ float fsub_s(float a, float b) {
#pragma clang fp contract(off)
  return a - b;
}

#if VSL_FMA
#define MULADD(a, b, c) __builtin_fmaf((a), (b), (c))
#else
#define MULADD(a, b, c) fadd_s(fmul_s((a), (b)), (c))
#endif

// --- Threefry-2x32, 20 rounds (exact JAX semantics) ---
static __device__ __forceinline__ uint32_t rotl(uint32_t v, uint32_t d) {
  return (v << d) | (v >> (32u - d));
}
static __device__ __forceinline__ void threefry2x32(uint32_t k0, uint32_t k1,
                                                    uint32_t x0, uint32_t x1,
                                                    uint32_t& o0, uint32_t& o1) {
  const uint32_t k2 = k0 ^ k1 ^ 0x1BD11BDAu;
  x0 += k0; x1 += k1;
#define TF_RD(r) { x0 += x1; x1 = rotl(x1, r); x1 ^= x0; }
  TF_RD(13u) TF_RD(15u) TF_RD(26u) TF_RD(6u)
  x0 += k1; x1 += k2 + 1u;
  TF_RD(17u) TF_RD(29u) TF_RD(16u) TF_RD(24u)
  x0 += k2; x1 += k0 + 2u;
  TF_RD(13u) TF_RD(15u) TF_RD(26u) TF_RD(6u)
  x0 += k0; x1 += k1 + 3u;
  TF_RD(17u) TF_RD(29u) TF_RD(16u) TF_RD(24u)
  x0 += k1; x1 += k2 + 4u;
  TF_RD(13u) TF_RD(15u) TF_RD(26u) TF_RD(6u)
  x0 += k2; x1 += k0 + 5u;
#undef TF_RD
  o0 = x0; o1 = x1;
}

// --- XLA CPU Cephes expf (GenerateVF32Exp) ---
static __device__ __forceinline__ float xla_expf(float input) {
  float x = fminf(input, 88.3762626647950f);
  x = fmaxf(x, -88.3762626647949f);
  float fx = floorf(MULADD(x, 1.44269504088896341f, 0.5f));
  float tmp = fmul_s(0.693359375f, fx);
  float z = fmul_s(-2.12194440e-4f, fx);
  x = fsub_s(x, tmp);
  x = fsub_s(x, z);
  z = fmul_s(x, x);
  float y = MULADD(x, 1.9875691500e-4f, 1.3981999507e-3f);
  y = MULADD(y, x, 8.3334519073e-3f);
  y = MULADD(y, x, 4.1665795894e-2f);
  y = MULADD(y, x, 1.6666665459e-1f);
  y = MULADD(y, x, 5.0000001201e-1f);
  y = MULADD(y, z, x);
  y = fadd_s(1.0f, y);
  int n = (int)fx;  // FPToSI; fx integral and clamped
  float p2n = __int_as_float((uint32_t)(n + 127) << 23);
  float res = fmul_s(y, p2n);
  return fmaxf(res, input);  // no-op in range, mirrors XLA
}

// --- XLA CPU Cephes logf (GenerateVF32Log); u in {0} U [2^-23, 1) here ---
static __device__ __forceinline__ float xla_logf(float u) {
  if (u == 0.0f) return -INFINITY;  // is_zero mask -> -inf
  uint32_t b = __float_as_uint(u);
  float e = (float)((int)(b >> 23) - 127) + 1.0f;  // sitofp(exp-0x7f) + 1
  float m = __uint_as_float((b & 0x007fffffu) | 0x3f000000u);  // [0.5, 1)
  if (m < 0.707106781186547524f) {
    e = fsub_s(e, 1.0f);
    m = fadd_s(m, m);
  }
  m = fsub_s(m, 1.0f);
  float z = fmul_s(m, m);
  float y = MULADD(m, 7.0376836292e-2f, -1.1514610310e-1f);
  y = MULADD(y, m, 1.1676998740e-1f);
  y = MULADD(y, m, -1.2420140846e-1f);
  y = MULADD(y, m, 1.4249322787e-1f);
  y = MULADD(y, m, -1.6668057665e-1f);
  y = MULADD(y, m, 2.0000714765e-1f);
  y = MULADD(y, m, -2.4999993993e-1f);
  y = MULADD(y, m, 3.3333331174e-1f);
  y = fmul_s(y, m);
  y = fmul_s(y, z);
  y = MULADD(e, -2.12194440e-4f, y);
  y = MULADD(z, -0.5f, y);  // == y - 0.5*z (exact either way when unfused)
  m = fadd_s(m, y);
  m = MULADD(e, 0.693359375f, m);
  return m;
}

// ============================================================================
// Kernel 1: per-time-step subkey chains.
// key_t = split(key(1), 1024)[t]; then (rng, subkey) = split(rng) J_MAX deep.
// sub layout: [t][j][2] u32.
// ============================================================================
__global__ void poglm_subkeys(uint32_t* __restrict__ sub) {
  int t = blockIdx.x * blockDim.x + threadIdx.x;
  if (t >= T_BINS) return;
  uint32_t kt0, kt1;
#if THREEFRY_PARTITIONABLE
  threefry2x32(0u, 1u, 0u, (uint32_t)t, kt0, kt1);
#else
  {  // original: bits = threefry(key, iota(2048)) split-halves; key_t = (bits[2t], bits[2t+1])
    uint32_t i0 = 2u * t, i1 = 2u * t + 1u, a0, a1, b0, b1;
    if (i0 < 1024u) { threefry2x32(0u, 1u, i0, i0 + 1024u, a0, a1); kt0 = a0; }
    else            { threefry2x32(0u, 1u, i0 - 1024u, i0, a0, a1); kt0 = a1; }
    if (i1 < 1024u) { threefry2x32(0u, 1u, i1, i1 + 1024u, b0, b1); kt1 = b0; }
    else            { threefry2x32(0u, 1u, i1 - 1024u, i1, b0, b1); kt1 = b1; }
  }
#endif
  uint32_t r0 = kt0, r1 = kt1;
  for (int j = 0; j < J_MAX; ++j) {
    uint32_t s0, s1, n0, n1;
#if THREEFRY_PARTITIONABLE
    threefry2x32(r0, r1, 0u, 1u, s0, s1);  // subkey = keys[1], counter (0,1)
    threefry2x32(r0, r1, 0u, 0u, n0, n1);  // new rng = keys[0], counter (0,0)
#else
    uint32_t p00, p01, p10, p11;  // counts iota(4): pairs (0,2) and (1,3)
    threefry2x32(r0, r1, 0u, 2u, p00, p01);
    threefry2x32(r0, r1, 1u, 3u, p10, p11);
    n0 = p00; n1 = p10;  // rng    = (out[0], out[1])
    s0 = p01; s1 = p11;  // subkey = (out[2], out[3])
#endif
    sub[(size_t)t * (2 * J_MAX) + 2 * j + 0] = s0;
    sub[(size_t)t * (2 * J_MAX) + 2 * j + 1] = s1;
    r0 = n0; r1 = n1;
  }
}

// ============================================================================
// Kernel 2: main simulation. Block = sample (64), thread = neuron (256).
// ============================================================================
__global__ __launch_bounds__(256, 1)
void poglm_main(const float* __restrict__ basis, const float* __restrict__ weight,
                const float* __restrict__ bias, const uint32_t* __restrict__ sub,
                float* __restrict__ out) {
  const int s = blockIdx.x;
  const int n = threadIdx.x;

  __shared__ float conv_lds[N_NEUR];
  __shared__ float fb_lds[20];          // flipped basis: fb[w] = basis[19-w]
  __shared__ uint32_t sk_lds[2 * J_MAX];

  if (n < 20) fb_lds[n] = basis[19 - n];
  const float bias_n = bias[n];
  const float4* __restrict__ w4 = reinterpret_cast<const float4*>(weight + (size_t)n * N_NEUR);

  float hist[20];  // hist[0] oldest (spk_{t-20}) ... hist[19] = spk_{t-1}
#pragma unroll
  for (int i = 0; i < 20; ++i) hist[i] = 0.0f;

  const uint32_t idx = (uint32_t)(s * N_NEUR + n);  // flat index in (64,256)
  const size_t plane = (size_t)N_SAMP * T_BINS * N_NEUR;
  float* __restrict__ out_spk = out + 0 * plane + (size_t)s * T_BINS * N_NEUR + n;
  float* __restrict__ out_cnv = out + 1 * plane + (size_t)s * T_BINS * N_NEUR + n;
  float* __restrict__ out_rte = out + 2 * plane + (size_t)s * T_BINS * N_NEUR + n;

  __syncthreads();

  for (int t = 0; t < T_BINS; ++t) {
    // stage this step's subkeys (uniform across block)
    if (n < 2 * J_MAX) sk_lds[n] = sub[(size_t)t * (2 * J_MAX) + n];

    // conv: ascending w, VSL tiled-gemv (unfused by default)
    float conv = 0.0f;
#pragma unroll
    for (int w = 0; w < 20; ++w) {
#if CONV_FMA
      conv = __builtin_fmaf(fb_lds[w], hist[w], conv);
#else
      conv = fadd_s(conv, fmul_s(fb_lds[w], hist[w]));
#endif
    }
    conv_lds[n] = conv;
    __syncthreads();

    // z = sum_k conv[k] * weight[n][k] (Eigen gemm: fused FMA, ascending k), + bias
    float zacc = 0.0f;
#pragma unroll 16
    for (int k4 = 0; k4 < N_NEUR / 4; ++k4) {
      float4 wv = w4[k4];
      zacc = __builtin_fmaf(conv_lds[4 * k4 + 0], wv.x, zacc);
      zacc = __builtin_fmaf(conv_lds[4 * k4 + 1], wv.y, zacc);
      zacc = __builtin_fmaf(conv_lds[4 * k4 + 2], wv.z, zacc);
      zacc = __builtin_fmaf(conv_lds[4 * k4 + 3], wv.w, zacc);
    }
    const float zb = fadd_s(zacc, bias_n);

    // lam = 1 / (1 + exp(-z))  (XLA logistic expander)
    const float lam = 1.0f / fadd_s(1.0f, xla_expf(-zb));
    const float neg_lam = -lam;

    // Knuth Poisson: r = #{ j>=1 : sum_{i<=j} log u_i > -lam }
    int r = 0;
    float S = 0.0f;
    for (int j = 0; j < J_MAX; ++j) {
      uint32_t o0, o1;
#if THREEFRY_PARTITIONABLE
      threefry2x32(sk_lds[2 * j], sk_lds[2 * j + 1], 0u, idx, o0, o1);
#if BITS32_XOR
      uint32_t bits = o0 ^ o1;
#else
      uint32_t bits = o1;
#endif
#else
      uint32_t bits;
      if (idx < 8192u) { threefry2x32(sk_lds[2 * j], sk_lds[2 * j + 1], idx, idx + 8192u, o0, o1); bits = o0; }
      else             { threefry2x32(sk_lds[2 * j], sk_lds[2 * j + 1], idx - 8192u, idx, o0, o1); bits = o1; }
#endif
      float u = __uint_as_float((bits >> 9) | 0x3f800000u) - 1.0f;  // [0,1)
      S = fadd_s(S, xla_logf(u));
      if (!(S > neg_lam)) break;
      ++r;
    }
    const float spk = (float)r;

    // shift history (static indices -> stays in VGPRs)
#pragma unroll
    for (int i = 0; i < 19; ++i) hist[i] = hist[i + 1];
    hist[19] = spk;

    const size_t off = (size_t)t * N_NEUR;
    out_spk[off] = spk;
    out_cnv[off] = conv;
    out_rte[off] = lam;
    __syncthreads();  // protect conv_lds/sk_lds for next step
  }
}

extern "C" void kernel_launch(void* const* d_in, const int* in_sizes, int n_in,
                              void* d_out, int out_size, void* d_ws, size_t ws_size,
                              hipStream_t stream) {
  const float* basis  = (const float*)d_in[0];
  const float* weight = (const float*)d_in[1];
  const float* bias   = (const float*)d_in[2];
  float* out = (float*)d_out;
  uint32_t* sub = (uint32_t*)d_ws;  // needs 1024 * 32 * 2 * 4 = 256 KiB

  hipLaunchKernelGGL(poglm_subkeys, dim3((T_BINS + 255) / 256), dim3(256), 0, stream, sub);
  hipLaunchKernelGGL(poglm_main, dim3(N_SAMP), dim3(256), 0, stream,
                     basis, weight, bias, sub, out);
}

// Round 2
// 4692.436 us; speedup vs baseline: 1.9312x; 1.9312x over previous
//
#include <hip/hip_runtime.h>
#include <stdint.h>
#include <math.h>

// ============================================================================
// POGLM.sample — bit-exact replication of the JAX-CPU reference.
// R2: weights-in-VGPRs, single raw barrier/step (no vmcnt drain),
//     double-buffered LDS, Poisson ILP batch x4. All computed values and
//     comparison sequences identical to R1 (verified-passing) kernel.
// Variant knobs:
#define THREEFRY_PARTITIONABLE 1
#define BITS32_XOR 1
#define VSL_FMA 0
#define CONV_FMA 0
#define RAW_BARRIER 1    // 1 = lgkmcnt-only barrier (no store drain)
#define POISSON_BATCH 4  // ILP batch width (1 = R1 behavior)
// ============================================================================

#define T_BINS 1024
#define N_SAMP 64
#define N_NEUR 256
#define J_MAX 32

// --- strict (non-contractable) f32 ops ---
static __device__ __forceinline__ float fmul_s(float a, float b) {
#pragma clang fp contract(off)
  return a * b;
}
static __device__ __forceinline__ float fadd_s(float a, float b) {
#pragma clang fp contract(off)
  return a + b;
}
static __device__ __forceinline__ float fsub_s(float a, float b) {
#pragma clang fp contract(off)
  return a - b;
}

#if VSL_FMA
#define MULADD(a, b, c) __builtin_fmaf((a), (b), (c))
#else
#define MULADD(a, b, c) fadd_s(fmul_s((a), (b)), (c))
#endif

// --- Threefry-2x32, 20 rounds (exact JAX semantics) ---
static __device__ __forceinline__ uint32_t rotl(uint32_t v, uint32_t d) {
  return (v << d) | (v >> (32u - d));
}
static __device__ __forceinline__ void threefry2x32(uint32_t k0, uint32_t k1,
                                                    uint32_t x0, uint32_t x1,
                                                    uint32_t& o0, uint32_t& o1) {
  const uint32_t k2 = k0 ^ k1 ^ 0x1BD11BDAu;
  x0 += k0; x1 += k1;
#define TF_RD(r) { x0 += x1; x1 = rotl(x1, r); x1 ^= x0; }
  TF_RD(13u) TF_RD(15u) TF_RD(26u) TF_RD(6u)
  x0 += k1; x1 += k2 + 1u;
  TF_RD(17u) TF_RD(29u) TF_RD(16u) TF_RD(24u)
  x0 += k2; x1 += k0 + 2u;
  TF_RD(13u) TF_RD(15u) TF_RD(26u) TF_RD(6u)
  x0 += k0; x1 += k1 + 3u;
  TF_RD(17u) TF_RD(29u) TF_RD(16u) TF_RD(24u)
  x0 += k1; x1 += k2 + 4u;
  TF_RD(13u) TF_RD(15u) TF_RD(26u) TF_RD(6u)
  x0 += k2; x1 += k0 + 5u;
#undef TF_RD
  o0 = x0; o1 = x1;
}

// --- XLA CPU Cephes expf (GenerateVF32Exp) ---
static __device__ __forceinline__ float xla_expf(float input) {
  float x = fminf(input, 88.3762626647950f);
  x = fmaxf(x, -88.3762626647949f);
  float fx = floorf(MULADD(x, 1.44269504088896341f, 0.5f));
  float tmp = fmul_s(0.693359375f, fx);
  float z = fmul_s(-2.12194440e-4f, fx);
  x = fsub_s(x, tmp);
  x = fsub_s(x, z);
  z = fmul_s(x, x);
  float y = MULADD(x, 1.9875691500e-4f, 1.3981999507e-3f);
  y = MULADD(y, x, 8.3334519073e-3f);
  y = MULADD(y, x, 4.1665795894e-2f);
  y = MULADD(y, x, 1.6666665459e-1f);
  y = MULADD(y, x, 5.0000001201e-1f);
  y = MULADD(y, z, x);
  y = fadd_s(1.0f, y);
  int n = (int)fx;
  float p2n = __int_as_float((uint32_t)(n + 127) << 23);
  float res = fmul_s(y, p2n);
  return fmaxf(res, input);
}

// --- XLA CPU Cephes logf (GenerateVF32Log); u in {0} U [2^-23, 1) here ---
static __device__ __forceinline__ float xla_logf(float u) {
  if (u == 0.0f) return -INFINITY;
  uint32_t b = __float_as_uint(u);
  float e = (float)((int)(b >> 23) - 127) + 1.0f;
  float m = __uint_as_float((b & 0x007fffffu) | 0x3f000000u);
  if (m < 0.707106781186547524f) {
    e = fsub_s(e, 1.0f);
    m = fadd_s(m, m);
  }
  m = fsub_s(m, 1.0f);
  float z = fmul_s(m, m);
  float y = MULADD(m, 7.0376836292e-2f, -1.1514610310e-1f);
  y = MULADD(y, m, 1.1676998740e-1f);
  y = MULADD(y, m, -1.2420140846e-1f);
  y = MULADD(y, m, 1.4249322787e-1f);
  y = MULADD(y, m, -1.6668057665e-1f);
  y = MULADD(y, m, 2.0000714765e-1f);
  y = MULADD(y, m, -2.4999993993e-1f);
  y = MULADD(y, m, 3.3333331174e-1f);
  y = fmul_s(y, m);
  y = fmul_s(y, z);
  y = MULADD(e, -2.12194440e-4f, y);
  y = MULADD(z, -0.5f, y);
  m = fadd_s(m, y);
  m = MULADD(e, 0.693359375f, m);
  return m;
}

// ============================================================================
// Kernel 1: per-time-step subkey chains. sub layout: [t][j][2] u32.
// ============================================================================
__global__ void poglm_subkeys(uint32_t* __restrict__ sub) {
  int t = blockIdx.x * blockDim.x + threadIdx.x;
  if (t >= T_BINS) return;
  uint32_t kt0, kt1;
#if THREEFRY_PARTITIONABLE
  threefry2x32(0u, 1u, 0u, (uint32_t)t, kt0, kt1);
#else
  {
    uint32_t i0 = 2u * t, i1 = 2u * t + 1u, a0, a1, b0, b1;
    if (i0 < 1024u) { threefry2x32(0u, 1u, i0, i0 + 1024u, a0, a1); kt0 = a0; }
    else            { threefry2x32(0u, 1u, i0 - 1024u, i0, a0, a1); kt0 = a1; }
    if (i1 < 1024u) { threefry2x32(0u, 1u, i1, i1 + 1024u, b0, b1); kt1 = b0; }
    else            { threefry2x32(0u, 1u, i1 - 1024u, i1, b0, b1); kt1 = b1; }
  }
#endif
  uint32_t r0 = kt0, r1 = kt1;
  for (int j = 0; j < J_MAX; ++j) {
    uint32_t s0, s1, n0, n1;
#if THREEFRY_PARTITIONABLE
    threefry2x32(r0, r1, 0u, 1u, s0, s1);
    threefry2x32(r0, r1, 0u, 0u, n0, n1);
#else
    uint32_t p00, p01, p10, p11;
    threefry2x32(r0, r1, 0u, 2u, p00, p01);
    threefry2x32(r0, r1, 1u, 3u, p10, p11);
    n0 = p00; n1 = p10;
    s0 = p01; s1 = p11;
#endif
    sub[(size_t)t * (2 * J_MAX) + 2 * j + 0] = s0;
    sub[(size_t)t * (2 * J_MAX) + 2 * j + 1] = s1;
    r0 = n0; r1 = n1;
  }
}

// ============================================================================
// Kernel 2: main simulation. Block = sample (64), thread = neuron (256).
// Weights live in VGPRs (256/thread). One raw barrier per step; conv_lds and
// sk_lds are parity double-buffered (max thread skew = 1 step => safe).
// ============================================================================
__global__ __launch_bounds__(256, 1)
void poglm_main(const float* __restrict__ basis, const float* __restrict__ weight,
                const float* __restrict__ bias, const uint32_t* __restrict__ sub,
                float* __restrict__ out) {
  const int s = blockIdx.x;
  const int n = threadIdx.x;

  __shared__ float conv_lds[2][N_NEUR];
  __shared__ uint32_t sk_lds[2][2 * J_MAX];
  __shared__ float fb_lds[20];  // fb[w] = basis[19-w]

  if (n < 20) fb_lds[n] = basis[19 - n];
  const float bias_n = bias[n];

  // Preload this neuron's weight row into registers (64 x float4 = 256 VGPR).
  const float4* __restrict__ w4 = reinterpret_cast<const float4*>(weight + (size_t)n * N_NEUR);
  float4 wreg[N_NEUR / 4];
#pragma unroll
  for (int k4 = 0; k4 < N_NEUR / 4; ++k4) wreg[k4] = w4[k4];

  float hist[20];
#pragma unroll
  for (int i = 0; i < 20; ++i) hist[i] = 0.0f;

  const uint32_t idx = (uint32_t)(s * N_NEUR + n);
  const size_t plane = (size_t)N_SAMP * T_BINS * N_NEUR;
  float* __restrict__ out_spk = out + 0 * plane + (size_t)s * T_BINS * N_NEUR + n;
  float* __restrict__ out_cnv = out + 1 * plane + (size_t)s * T_BINS * N_NEUR + n;
  float* __restrict__ out_rte = out + 2 * plane + (size_t)s * T_BINS * N_NEUR + n;

  // Prefetch step-0 subkeys into a register (lanes 0..63 of wave 0).
  uint32_t skreg = 0;
  if (n < 2 * J_MAX) skreg = sub[n];

  __syncthreads();  // fb_lds visible (once; vmcnt drain here is harmless)

  for (int t = 0; t < T_BINS; ++t) {
    const int buf = t & 1;
    // Stage this step's subkeys (value prefetched last step -> ds_write waits
    // only vmcnt(small), never a full drain), then issue next step's load.
    if (n < 2 * J_MAX) {
      sk_lds[buf][n] = skreg;
      const int tn = (t + 1 < T_BINS) ? t + 1 : t;
      skreg = sub[(size_t)tn * (2 * J_MAX) + n];
    }

    // conv: ascending w, unfused mul+add (order bit-locked)
    float conv = 0.0f;
#pragma unroll
    for (int w = 0; w < 20; ++w) {
#if CONV_FMA
      conv = __builtin_fmaf(fb_lds[w], hist[w], conv);
#else
      conv = fadd_s(conv, fmul_s(fb_lds[w], hist[w]));
#endif
    }
    conv_lds[buf][n] = conv;

#if RAW_BARRIER
    // LDS-only fence + barrier: does NOT drain outstanding global stores.
    asm volatile("s_waitcnt lgkmcnt(0)\n\ts_barrier" ::: "memory");
#else
    __syncthreads();
#endif

    // z = sum_k conv[k]*W[n][k], fused FMA ascending k (order bit-locked), + bias
    float zacc = 0.0f;
#pragma unroll
    for (int k4 = 0; k4 < N_NEUR / 4; ++k4) {
      const float4 wv = wreg[k4];
      zacc = __builtin_fmaf(conv_lds[buf][4 * k4 + 0], wv.x, zacc);
      zacc = __builtin_fmaf(conv_lds[buf][4 * k4 + 1], wv.y, zacc);
      zacc = __builtin_fmaf(conv_lds[buf][4 * k4 + 2], wv.z, zacc);
      zacc = __builtin_fmaf(conv_lds[buf][4 * k4 + 3], wv.w, zacc);
    }
    const float zb = fadd_s(zacc, bias_n);

    // lam = 1 / (1 + exp(-z))
    const float lam = 1.0f / fadd_s(1.0f, xla_expf(-zb));
    const float neg_lam = -lam;

    // Knuth Poisson, ILP-batched: values & comparison sequence identical to
    // the sequential form; batches only precompute independent log u_j.
    int r = 0;
    float S = 0.0f;
    bool done = false;
    for (int jb = 0; jb < J_MAX; jb += POISSON_BATCH) {
      float L[POISSON_BATCH];
#pragma unroll
      for (int q = 0; q < POISSON_BATCH; ++q) {
        const int j = jb + q;
        uint32_t o0, o1;
        threefry2x32(sk_lds[buf][2 * j], sk_lds[buf][2 * j + 1], 0u, idx, o0, o1);
#if BITS32_XOR
        const uint32_t bits = o0 ^ o1;
#else
        const uint32_t bits = o1;
#endif
        const float u = __uint_as_float((bits >> 9) | 0x3f800000u) - 1.0f;
        L[q] = xla_logf(u);
      }
#pragma unroll
      for (int q = 0; q < POISSON_BATCH; ++q) {
        if (!done) {
          S = fadd_s(S, L[q]);
          if (S > neg_lam) ++r; else done = true;
        }
      }
      if (__all(done)) break;
    }
    const float spk = (float)r;

#pragma unroll
    for (int i = 0; i < 19; ++i) hist[i] = hist[i + 1];
    hist[19] = spk;

    const size_t off = (size_t)t * N_NEUR;
    out_spk[off] = spk;
    out_cnv[off] = conv;
    out_rte[off] = lam;
#if !RAW_BARRIER
    __syncthreads();
#endif
  }
}

extern "C" void kernel_launch(void* const* d_in, const int* in_sizes, int n_in,
                              void* d_out, int out_size, void* d_ws, size_t ws_size,
                              hipStream_t stream) {
  const float* basis  = (const float*)d_in[0];
  const float* weight = (const float*)d_in[1];
  const float* bias   = (const float*)d_in[2];
  float* out = (float*)d_out;
  uint32_t* sub = (uint32_t*)d_ws;  // 1024 * 32 * 2 * 4 = 256 KiB

  hipLaunchKernelGGL(poglm_subkeys, dim3((T_BINS + 255) / 256), dim3(256), 0, stream, sub);
  hipLaunchKernelGGL(poglm_main, dim3(N_SAMP), dim3(256), 0, stream,
                     basis, weight, bias, sub, out);
}